// Round 13
// baseline (717.920 us; speedup 1.0000x reference)
//
#include <hip/hip_runtime.h>

#define DEV __device__ __forceinline__

namespace {

typedef __attribute__((ext_vector_type(8))) short short8;
typedef __attribute__((ext_vector_type(4))) float f32x4;
typedef __attribute__((ext_vector_type(2))) float f32x2;

constexpr int B_ = 16, N_ = 4096, S_ = 512, CF_ = 64;
constexpr float EPS_ = 1e-5f;

// ---- ws layout (float units) ----
constexpr int IDX0_OFF  = 0;                      // B*S*32 ints
constexpr int IDX1_OFF  = 262144;                 // B*S*64 ints
constexpr int STATS_OFF = IDX1_OFF + 524288;      // 6 stages * 32 copies * 256 f
constexpr int WP_OFF    = STATS_OFF + 49152;      // 43008 ushorts = 21504 f
constexpr int MAXTA_OFF = WP_OFF + 21504;         // 8192*128 f
constexpr int MAXTB_OFF = MAXTA_OFF + 1048576;    // 8192*128 f
constexpr int FEATT_OFF = MAXTB_OFF + 1048576;    // 4194304 ushorts
constexpr int YA_OFF    = FEATT_OFF + 2097152;    // 262144*64 us = 8388608 f
constexpr int YB_OFF    = YA_OFF + 8388608;       // 524288*64 us = 16777216 f
constexpr int YC_OFF    = YB_OFF + 16777216;      // 262144*64 us = 8388608 f
constexpr int YD_OFF    = YC_OFF + 8388608;       // 524288*96 us = 25165824 f
// total = 255 MB (< proven 268 MB)

// packed-weight sub-offsets (ushort units)
constexpr int WP00 = 0,     WP01 = 6144,  WP02 = 10240;
constexpr int WP10 = 18432, WP11 = 24576, WP12 = 30720;

constexpr float N0F = (float)(B_ * S_ * 32);
constexpr float N1F = (float)(B_ * S_ * 64);

DEV int rfl(int x) { return __builtin_amdgcn_readfirstlane(x); }

DEV unsigned short f2bf(float x) {  // RNE float->bf16
  unsigned u = __float_as_uint(x);
  u += 0x7fff + ((u >> 16) & 1);
  return (unsigned short)(u >> 16);
}
DEV float bf2f(unsigned short u) { return __uint_as_float((unsigned)u << 16); }

// 64-lane f32 max reduce via DPP; full-wave max valid in lane 63.
DEV float dpp_max64(float v) {
  int m;
  m = __builtin_amdgcn_update_dpp(__float_as_int(v), __float_as_int(v), 0xB1, 0xf, 0xf, false);
  v = fmaxf(v, __int_as_float(m));
  m = __builtin_amdgcn_update_dpp(__float_as_int(v), __float_as_int(v), 0x4E, 0xf, 0xf, false);
  v = fmaxf(v, __int_as_float(m));
  m = __builtin_amdgcn_update_dpp(__float_as_int(v), __float_as_int(v), 0x141, 0xf, 0xf, false);
  v = fmaxf(v, __int_as_float(m));
  m = __builtin_amdgcn_update_dpp(__float_as_int(v), __float_as_int(v), 0x140, 0xf, 0xf, false);
  v = fmaxf(v, __int_as_float(m));
  m = __builtin_amdgcn_update_dpp(__float_as_int(v), __float_as_int(v), 0x142, 0xa, 0xf, false);
  v = fmaxf(v, __int_as_float(m));
  m = __builtin_amdgcn_update_dpp(__float_as_int(v), __float_as_int(v), 0x143, 0xc, 0xf, false);
  v = fmaxf(v, __int_as_float(m));
  return v;
}

// ===================== FPS body: 2 batches per block, interleaved serial chains ==========
DEV void fps_body2(char* smem, const float* __restrict__ xyz, float* __restrict__ newxyz,
                   int bb) {
  float* pxA = (float*)smem;  // 6 * 16 KB coord arrays
  float* pyA = pxA + N_;
  float* pzA = pyA + N_;
  float* pxB = pzA + N_;
  float* pyB = pxB + N_;
  float* pzB = pyB + N_;                                          // ends at 98304 B
  unsigned long long* swk = (unsigned long long*)(smem + 98304);  // [2][8] = 128 B
  int* seqA = (int*)(smem + 98432);                               // 512 ints
  int* seqB = (int*)(smem + 100480);                              // 512 ints
  const int t = threadIdx.x, lane = t & 63, wv = t >> 6;
  const float* xbA = xyz + (size_t)(2 * bb) * N_ * 3;
  const float* xbB = xyz + (size_t)(2 * bb + 1) * N_ * 3;
  for (int i = t; i < N_; i += 256) {
    pxA[i] = xbA[i * 3 + 0];
    pyA[i] = xbA[i * 3 + 1];
    pzA[i] = xbA[i * 3 + 2];
    pxB[i] = xbB[i * 3 + 0];
    pyB[i] = xbB[i * 3 + 1];
    pzB[i] = xbB[i * 3 + 2];
  }
  __syncthreads();
  f32x2 XA[8], YA[8], ZA[8], DA[8], XB[8], YB[8], ZB[8], DB[8];
#pragma unroll
  for (int jp = 0; jp < 8; ++jp) {
    XA[jp] = *reinterpret_cast<const f32x2*>(&pxA[t * 16 + jp * 2]);
    YA[jp] = *reinterpret_cast<const f32x2*>(&pyA[t * 16 + jp * 2]);
    ZA[jp] = *reinterpret_cast<const f32x2*>(&pzA[t * 16 + jp * 2]);
    XB[jp] = *reinterpret_cast<const f32x2*>(&pxB[t * 16 + jp * 2]);
    YB[jp] = *reinterpret_cast<const f32x2*>(&pyB[t * 16 + jp * 2]);
    ZB[jp] = *reinterpret_cast<const f32x2*>(&pzB[t * 16 + jp * 2]);
    DA[jp] = f32x2{1e10f, 1e10f};
    DB[jp] = f32x2{1e10f, 1e10f};
  }
  float cxA = pxA[0], cyA = pyA[0], czA = pzA[0];
  float cxB = pxB[0], cyB = pyB[0], czB = pzB[0];
  if (t == 0) { seqA[0] = 0; seqB[0] = 0; }
  for (int it = 1; it < S_; ++it) {
    const int p = it & 1;
    f32x2 bvpA = {-1.0f, -1.0f}, bvpB = {-1.0f, -1.0f};
    {
#pragma clang fp contract(off)
      const f32x2 cax = {cxA, cxA}, cay = {cyA, cyA}, caz = {czA, czA};
      const f32x2 cbx = {cxB, cxB}, cby = {cyB, cyB}, cbz = {czB, czB};
#pragma unroll
      for (int jp = 0; jp < 8; ++jp) {
        const f32x2 dxa = XA[jp] - cax, dya = YA[jp] - cay, dza = ZA[jp] - caz;
        const f32x2 da = (dxa * dxa + dya * dya) + dza * dza;
        DA[jp] = __builtin_elementwise_min(DA[jp], da);
        bvpA = __builtin_elementwise_max(bvpA, DA[jp]);
        const f32x2 dxb = XB[jp] - cbx, dyb = YB[jp] - cby, dzb = ZB[jp] - cbz;
        const f32x2 db = (dxb * dxb + dyb * dyb) + dzb * dzb;
        DB[jp] = __builtin_elementwise_min(DB[jp], db);
        bvpB = __builtin_elementwise_max(bvpB, DB[jp]);
      }
    }
    const float bvA = fmaxf(bvpA.x, bvpA.y);
    const float bvB = fmaxf(bvpB.x, bvpB.y);
    int bjA = 0, bjB = 0;
#pragma unroll
    for (int j = 15; j >= 0; --j) {  // serial cndmask scans (R10-proven); A/B interleave
      bjA = (DA[j >> 1][j & 1] == bvA) ? j : bjA;
      bjB = (DB[j >> 1][j & 1] == bvB) ? j : bjB;
    }
    const int biA = t * 16 + bjA;
    const int biB = t * 16 + bjB;
    const float mxlA = dpp_max64(bvA);
    const float mxlB = dpp_max64(bvB);
    const float mxA = __int_as_float(__builtin_amdgcn_readlane(__float_as_int(mxlA), 63));
    const float mxB = __int_as_float(__builtin_amdgcn_readlane(__float_as_int(mxlB), 63));
    const unsigned long long tieA = __ballot(bvA == mxA);
    const unsigned long long tieB = __ballot(bvB == mxB);
    const int wbiA = __builtin_amdgcn_readlane(biA, (int)__builtin_ctzll(tieA));
    const int wbiB = __builtin_amdgcn_readlane(biB, (int)__builtin_ctzll(tieB));
    if (lane == 0) {
      swk[p * 8 + wv] = ((unsigned long long)__float_as_uint(mxA) << 32) | (unsigned)(~wbiA);
      swk[p * 8 + 4 + wv] = ((unsigned long long)__float_as_uint(mxB) << 32) | (unsigned)(~wbiB);
    }
    __syncthreads();
    const unsigned long long a0 = swk[p * 8 + 0], a1 = swk[p * 8 + 1];
    const unsigned long long a2 = swk[p * 8 + 2], a3 = swk[p * 8 + 3];
    const unsigned long long b0 = swk[p * 8 + 4], b1 = swk[p * 8 + 5];
    const unsigned long long b2 = swk[p * 8 + 6], b3 = swk[p * 8 + 7];
    const unsigned long long aa = a0 > a1 ? a0 : a1;
    const unsigned long long ab = a2 > a3 ? a2 : a3;
    const unsigned long long kwA = aa > ab ? aa : ab;
    const unsigned long long ba = b0 > b1 ? b0 : b1;
    const unsigned long long bbq = b2 > b3 ? b2 : b3;
    const unsigned long long kwB = ba > bbq ? ba : bbq;
    const int riA = (int)(~(unsigned)kwA);
    const int riB = (int)(~(unsigned)kwB);
    cxA = pxA[riA]; cyA = pyA[riA]; czA = pzA[riA];
    cxB = pxB[riB]; cyB = pyB[riB]; czB = pzB[riB];
    if (t == 0) { seqA[it] = riA; seqB[it] = riB; }
  }
  __syncthreads();
  for (int i = t; i < S_; i += 256) {
    const int riA = seqA[i];
    const int riB = seqB[i];
    newxyz[(size_t)((2 * bb) * S_ + i) * 3 + 0] = pxA[riA];
    newxyz[(size_t)((2 * bb) * S_ + i) * 3 + 1] = pyA[riA];
    newxyz[(size_t)((2 * bb) * S_ + i) * 3 + 2] = pzA[riA];
    newxyz[(size_t)((2 * bb + 1) * S_ + i) * 3 + 0] = pxB[riB];
    newxyz[(size_t)((2 * bb + 1) * S_ + i) * 3 + 1] = pyB[riB];
    newxyz[(size_t)((2 * bb + 1) * S_ + i) * 3 + 2] = pzB[riB];
  }
}

// ===================== prep body (256 threads): stats zero + pack + transpose ============
DEV void prep_body(char* smem, int pb, const float* __restrict__ feat,
                   unsigned short* __restrict__ featT,
                   const float* __restrict__ w00, const float* __restrict__ w01,
                   const float* __restrict__ w02, const float* __restrict__ w10,
                   const float* __restrict__ w11, const float* __restrict__ w12,
                   unsigned short* __restrict__ wp, float* __restrict__ stats) {
  const int t = threadIdx.x;
  if (pb < 24) {
    for (int i = pb * 2048 + t; i < (pb + 1) * 2048; i += 256) stats[i] = 0.f;
  }
  {
    const int id = pb * 256 + t;
    const float* w = nullptr; int off = 0, KK = 0, CINW = 0, base = 0; bool perm = false;
    if (id < 768)       { w = w00; off = WP00; KK = 3; CINW = 67; perm = true;  base = 0; }
    else if (id < 1280) { w = w01; off = WP01; KK = 2; CINW = 64; perm = false; base = 768; }
    else if (id < 2304) { w = w02; off = WP02; KK = 2; CINW = 64; perm = false; base = 1280; }
    else if (id < 3072) { w = w10; off = WP10; KK = 3; CINW = 67; perm = true;  base = 2304; }
    else if (id < 3840) { w = w11; off = WP11; KK = 2; CINW = 64; perm = false; base = 3072; }
    else if (id < 5376) { w = w12; off = WP12; KK = 3; CINW = 96; perm = false; base = 3840; }
    if (w) {
      const int lid = id - base;
      const int lane = lid & 63, fr = lid >> 6;
      const int kk = fr % KK, nt = fr / KK;
      const int ccol = nt * 16 + (lane & 15);
      const int kbase = kk * 32 + (lane >> 4) * 8;
      unsigned short* dst = wp + off + (size_t)lid * 8;
#pragma unroll
      for (int j = 0; j < 8; ++j) {
        const int kq = kbase + j;
        int cin;
        if (perm) cin = (kq < 64) ? kq + 3 : (kq < 67 ? kq - 64 : -1);
        else      cin = (kq < CINW) ? kq : -1;
        float f = (cin >= 0) ? w[ccol * CINW + cin] : 0.f;
        dst[j] = f2bf(f);
      }
    }
  }
  {  // feat transpose (pb in [0,1024))
    unsigned short(*tile)[65] = (unsigned short(*)[65])smem;
    const int b = pb >> 6, nc = pb & 63;
    const int n0 = nc * 64;
    for (int i = t; i < 4096; i += 256) {
      int c = i >> 6, n = i & 63;
      tile[c][n] = f2bf(feat[((size_t)b * CF_ + c) * N_ + n0 + n]);
    }
    __syncthreads();
    for (int i = t; i < 4096; i += 256) {
      int n = i >> 6, c = i & 63;
      featT[((size_t)b * N_ + n0 + n) * 64 + c] = tile[c][n];
    }
  }
}

__global__ __launch_bounds__(256) void prep_fps_kernel(
    const float* __restrict__ xyz, float* __restrict__ newxyz,
    const float* __restrict__ feat, unsigned short* __restrict__ featT,
    const float* __restrict__ w00, const float* __restrict__ w01,
    const float* __restrict__ w02, const float* __restrict__ w10,
    const float* __restrict__ w11, const float* __restrict__ w12,
    unsigned short* __restrict__ wp, float* __restrict__ stats) {
  __shared__ __align__(16) char smem[102528];
  if (blockIdx.x < 8)
    fps_body2(smem, xyz, newxyz, blockIdx.x);
  else
    prep_body(smem, blockIdx.x - 8, feat, featT, w00, w01, w02, w10, w11, w12, wp, stats);
}

// ===================== Ball query (both scales) =====================
DEV void ballq_dev(const float* __restrict__ xyz, const float* __restrict__ newxyz,
                   int* __restrict__ idx0, int* __restrict__ idx1, int* my, int gw, int NW) {
  const int lane = threadIdx.x & 63;
  for (int csp = gw; csp < 16384; csp += NW) {
    const int scale = csp >> 13;
    const int cs = csp & 8191;
    const int NS = scale ? 64 : 32;
    const float r2 = scale ? 0.4f * 0.4f : 0.2f * 0.2f;
    int* __restrict__ idx = scale ? idx1 : idx0;
    const int b = cs >> 9;
    const float cx = newxyz[(size_t)cs * 3 + 0];
    const float cy = newxyz[(size_t)cs * 3 + 1];
    const float cz = newxyz[(size_t)cs * 3 + 2];
    const float* xb = xyz + (size_t)b * N_ * 3;
    int cnt = 0;
    for (int base = 0; base < N_; base += 64) {
      if (cnt >= NS) break;
      const int i = base + lane;
      float d;
      {
#pragma clang fp contract(off)
        float dx = xb[i * 3 + 0] - cx, dy = xb[i * 3 + 1] - cy, dz = xb[i * 3 + 2] - cz;
        d = (dx * dx + dy * dy) + dz * dz;
      }
      const bool q = d < r2;
      const unsigned long long m = __ballot(q);
      if (q) {
        int pos = cnt + __popcll(m & ((1ull << lane) - 1ull));
        if (pos < NS) my[pos] = i;
      }
      cnt += __popcll(m);
    }
    const int c = cnt < NS ? cnt : NS;
    const int first = my[0];
    for (int j = lane; j < NS; j += 64) idx[(size_t)cs * NS + j] = (j < c) ? my[j] : first;
  }
}

__global__ __launch_bounds__(256) void ballq_kernel(const float* __restrict__ xyz,
                                                    const float* __restrict__ newxyz,
                                                    int* __restrict__ idx0,
                                                    int* __restrict__ idx1) {
  __shared__ int sbuf[4][64];
  const int wiv = threadIdx.x >> 6;
  const int gw = blockIdx.x * 4 + rfl(wiv);
  ballq_dev(xyz, newxyz, idx0, idx1, sbuf[wiv], gw, 16384);
}

// ===================== stats helpers (32-copy spread) =====================
template <int DS>
DEV void flush_stats(const float* ssum, const float* ssq, int lane, int slot,
                     float* __restrict__ sg) {
  constexpr int NTS = DS / 16;
  float* dst = sg + (size_t)slot * 256;
#pragma unroll
  for (int nt = 0; nt < NTS; ++nt) {
    float s = ssum[nt], q = ssq[nt];
    s += __shfl_xor(s, 16); q += __shfl_xor(q, 16);
    s += __shfl_xor(s, 32); q += __shfl_xor(q, 32);
    if (lane < 16) {
      atomicAdd(&dst[nt * 16 + lane], s);
      atomicAdd(&dst[DS + nt * 16 + lane], q);
    }
  }
}

DEV void reduce_stats_block(const float* __restrict__ sg, float* sstats, int t) {
  float s = 0.f;
#pragma unroll
  for (int c = 0; c < 32; ++c) s += sg[c * 256 + t];
  sstats[t] = s;
  __syncthreads();
}

// ===================== P1: gather + layer0 =====================
template <int K>
DEV void p1_dev(const float* __restrict__ xyz, const unsigned short* __restrict__ featT,
                const float* __restrict__ newxyz, const int* __restrict__ idx,
                const unsigned short* __restrict__ wp0, const float* __restrict__ b0,
                unsigned short* __restrict__ y0, float* __restrict__ stats_out,
                int gw, int NW) {
  const int lane = threadIdx.x & 63;
  const int col = lane & 15, khi = lane >> 4;
  constexpr int MT = (B_ * S_ * K) / 16;
  short8 bfr[12];
#pragma unroll
  for (int i = 0; i < 12; ++i)
    bfr[i] = *reinterpret_cast<const short8*>(wp0 + ((size_t)i * 64 + lane) * 8);
  float bb[4];
#pragma unroll
  for (int nt = 0; nt < 4; ++nt) bb[nt] = b0[nt * 16 + col];
  float ssum[4] = {0.f, 0.f, 0.f, 0.f}, ssq[4] = {0.f, 0.f, 0.f, 0.f};
  for (int mt = gw; mt < MT; mt += NW) {
    const int row = mt * 16 + col;
    const int cs = row / K;
    const int b = cs >> 9;
    const int pi = idx[row];
    const unsigned short* fr = featT + (((size_t)b * N_ + pi) << 6);
    const short8 a0 = *reinterpret_cast<const short8*>(fr + khi * 8);
    const short8 a1 = *reinterpret_cast<const short8*>(fr + 32 + khi * 8);
    short8 a2 = {0, 0, 0, 0, 0, 0, 0, 0};
    if (khi == 0) {
      const float* P = xyz + ((size_t)b * N_ + pi) * 3;
      const float* C = newxyz + (size_t)cs * 3;
      a2[0] = (short)f2bf(P[0] - C[0]);
      a2[1] = (short)f2bf(P[1] - C[1]);
      a2[2] = (short)f2bf(P[2] - C[2]);
    }
#pragma unroll
    for (int nt = 0; nt < 4; ++nt) {
      f32x4 a = {0.f, 0.f, 0.f, 0.f};
      a = __builtin_amdgcn_mfma_f32_16x16x32_bf16(a0, bfr[nt * 3 + 0], a, 0, 0, 0);
      a = __builtin_amdgcn_mfma_f32_16x16x32_bf16(a1, bfr[nt * 3 + 1], a, 0, 0, 0);
      a = __builtin_amdgcn_mfma_f32_16x16x32_bf16(a2, bfr[nt * 3 + 2], a, 0, 0, 0);
#pragma unroll
      for (int j = 0; j < 4; ++j) {
        const float y = a[j] + bb[nt];
        ssum[nt] += y; ssq[nt] += y * y;
        y0[(size_t)(mt * 16 + khi * 4 + j) * 64 + nt * 16 + col] = f2bf(y);
      }
    }
  }
  flush_stats<64>(ssum, ssq, lane, gw & 31, stats_out);
}

// ===================== P2: stats-reduce + norm -> layer -> yout =====================
template <int DIN, int DOUT>
DEV void p2_dev(const unsigned short* __restrict__ yin, const unsigned short* __restrict__ wp,
                const float* __restrict__ bias, const float* __restrict__ gprev,
                const float* __restrict__ bprev, const float* __restrict__ stats_prev, float n,
                unsigned short* __restrict__ yout, float* __restrict__ stats_out, int MT,
                float* sstats, int gw, int NW) {
  constexpr int KK = DIN / 32, NT = DOUT / 16;
  const int t = threadIdx.x, lane = t & 63;
  const int col = lane & 15, khi = lane >> 4;
  reduce_stats_block(stats_prev, sstats, t);
  short8 bfr[NT * KK];
#pragma unroll
  for (int i = 0; i < NT * KK; ++i)
    bfr[i] = *reinterpret_cast<const short8*>(wp + ((size_t)i * 64 + lane) * 8);
  float bb[NT];
#pragma unroll
  for (int nt = 0; nt < NT; ++nt) bb[nt] = bias[nt * 16 + col];
  float ar[KK][8], cr[KK][8];
#pragma unroll
  for (int kk = 0; kk < KK; ++kk)
#pragma unroll
    for (int j = 0; j < 8; ++j) {
      const int ch = kk * 32 + khi * 8 + j;
      const float mu = sstats[ch] / n;
      const float var = sstats[DIN + ch] / n - mu * mu;
      const float a = gprev[ch] / sqrtf(var + EPS_);
      ar[kk][j] = a;
      cr[kk][j] = bprev[ch] - mu * a;
    }
  float ssum[NT], ssq[NT];
#pragma unroll
  for (int nt = 0; nt < NT; ++nt) { ssum[nt] = 0.f; ssq[nt] = 0.f; }
  for (int mt = gw; mt < MT; mt += NW) {
    const size_t rb = (size_t)(mt * 16 + col) * DIN;
    short8 af[KK];
#pragma unroll
    for (int kk = 0; kk < KK; ++kk) {
      const short8 raw = *reinterpret_cast<const short8*>(yin + rb + kk * 32 + khi * 8);
#pragma unroll
      for (int j = 0; j < 8; ++j) {
        const float v = bf2f((unsigned short)raw[j]) * ar[kk][j] + cr[kk][j];
        af[kk][j] = (short)f2bf(fmaxf(v, 0.f));
      }
    }
#pragma unroll
    for (int nt = 0; nt < NT; ++nt) {
      f32x4 a = {0.f, 0.f, 0.f, 0.f};
#pragma unroll
      for (int kk = 0; kk < KK; ++kk)
        a = __builtin_amdgcn_mfma_f32_16x16x32_bf16(af[kk], bfr[nt * KK + kk], a, 0, 0, 0);
#pragma unroll
      for (int j = 0; j < 4; ++j) {
        const float y = a[j] + bb[nt];
        ssum[nt] += y; ssq[nt] += y * y;
        yout[(size_t)(mt * 16 + khi * 4 + j) * DOUT + nt * 16 + col] = f2bf(y);
      }
    }
  }
  flush_stats<DOUT>(ssum, ssq, lane, gw & 31, stats_out);
}

// ===================== P3: stats-reduce + norm -> layer2 -> stats + k-max ==========
template <int DIN, int K>
DEV void p3_dev(const unsigned short* __restrict__ yin, const unsigned short* __restrict__ wp,
                const float* __restrict__ bias, const float* __restrict__ gprev,
                const float* __restrict__ bprev, const float* __restrict__ stats_prev, float n,
                float* __restrict__ maxtmp, float* __restrict__ stats_out,
                float* sstats, int gw, int NW) {
  constexpr int KK = DIN / 32, NT = 8;
  const int t = threadIdx.x, lane = t & 63;
  const int col = lane & 15, khi = lane >> 4;
  reduce_stats_block(stats_prev, sstats, t);
  float bb[NT];
#pragma unroll
  for (int nt = 0; nt < NT; ++nt) bb[nt] = bias[nt * 16 + col];
  float ar[KK][8], cr[KK][8];
#pragma unroll
  for (int kk = 0; kk < KK; ++kk)
#pragma unroll
    for (int j = 0; j < 8; ++j) {
      const int ch = kk * 32 + khi * 8 + j;
      const float mu = sstats[ch] / n;
      const float var = sstats[DIN + ch] / n - mu * mu;
      const float a = gprev[ch] / sqrtf(var + EPS_);
      ar[kk][j] = a;
      cr[kk][j] = bprev[ch] - mu * a;
    }
  float ssum[NT], ssq[NT];
#pragma unroll
  for (int nt = 0; nt < NT; ++nt) { ssum[nt] = 0.f; ssq[nt] = 0.f; }
  for (int c = gw; c < B_ * S_; c += NW) {
    float mx[NT];
#pragma unroll
    for (int nt = 0; nt < NT; ++nt) mx[nt] = -3.4e38f;
#pragma unroll
    for (int m = 0; m < K / 16; ++m) {
      const size_t rb = (size_t)(c * K + m * 16 + col) * DIN;
      short8 af[KK];
#pragma unroll
      for (int kk = 0; kk < KK; ++kk) {
        const short8 raw = *reinterpret_cast<const short8*>(yin + rb + kk * 32 + khi * 8);
#pragma unroll
        for (int j = 0; j < 8; ++j) {
          const float v = bf2f((unsigned short)raw[j]) * ar[kk][j] + cr[kk][j];
          af[kk][j] = (short)f2bf(fmaxf(v, 0.f));
        }
      }
#pragma unroll
      for (int nt = 0; nt < NT; ++nt) {
        f32x4 a = {0.f, 0.f, 0.f, 0.f};
#pragma unroll
        for (int kk = 0; kk < KK; ++kk) {
          const short8 bf =
              *reinterpret_cast<const short8*>(wp + ((size_t)(nt * KK + kk) * 64 + lane) * 8);
          a = __builtin_amdgcn_mfma_f32_16x16x32_bf16(af[kk], bf, a, 0, 0, 0);
        }
#pragma unroll
        for (int j = 0; j < 4; ++j) {
          const float y = a[j] + bb[nt];
          ssum[nt] += y; ssq[nt] += y * y;
          mx[nt] = fmaxf(mx[nt], y);
        }
      }
    }
#pragma unroll
    for (int nt = 0; nt < NT; ++nt) {
      mx[nt] = fmaxf(mx[nt], __shfl_xor(mx[nt], 16));
      mx[nt] = fmaxf(mx[nt], __shfl_xor(mx[nt], 32));
    }
    if (lane < 16) {
#pragma unroll
      for (int nt = 0; nt < NT; ++nt) maxtmp[(size_t)c * 128 + nt * 16 + lane] = mx[nt];
    }
  }
  flush_stats<128>(ssum, ssq, lane, gw & 31, stats_out);
}

// ===================== out: stats-reduce + affine + transpose-write =====================
DEV void out_dev(const float* __restrict__ maxtmp, const float* __restrict__ stats2,
                 const float* __restrict__ g2, const float* __restrict__ be2, float n,
                 float* __restrict__ outf, int coff, float* sstats, int start, int stride) {
  reduce_stats_block(stats2, sstats, threadIdx.x);
  for (int i = start; i < B_ * 128 * S_; i += stride) {
    const int s = i & 511;
    const int o = (i >> 9) & 127;
    const int b = i >> 16;
    const float mu = sstats[o] / n;
    const float var = sstats[128 + o] / n - mu * mu;
    const float a = g2[o] / sqrtf(var + EPS_);
    const float c = be2[o] - mu * a;
    const float v = maxtmp[((size_t)(b * S_ + s)) * 128 + o];
    outf[((size_t)b * 256 + coff + o) * S_ + s] = a * v + c;
  }
}

// ===================== phase kernels =====================
__global__ __launch_bounds__(256) void p1_both_kernel(
    const float* __restrict__ xyz, const unsigned short* __restrict__ featT,
    const float* __restrict__ newxyz, const int* __restrict__ idx0,
    const int* __restrict__ idx1, const unsigned short* __restrict__ wp,
    const float* __restrict__ b00, const float* __restrict__ b10,
    unsigned short* __restrict__ yA, unsigned short* __restrict__ yB,
    float* __restrict__ st0, float* __restrict__ st3) {
  const int wid = rfl(threadIdx.x >> 6);
  if (blockIdx.x < 1024)
    p1_dev<32>(xyz, featT, newxyz, idx0, wp + WP00, b00, yA, st0, blockIdx.x * 4 + wid, 4096);
  else
    p1_dev<64>(xyz, featT, newxyz, idx1, wp + WP10, b10, yB, st3,
               (blockIdx.x - 1024) * 4 + wid, 8192);
}

__global__ __launch_bounds__(256) void p2s0_kernel(
    const unsigned short* __restrict__ yA, const unsigned short* __restrict__ wp,
    const float* __restrict__ b01, const float* __restrict__ g00,
    const float* __restrict__ be00, const float* __restrict__ st0,
    unsigned short* __restrict__ yC, float* __restrict__ st1) {
  __shared__ float sstats[256];
  const int wid = rfl(threadIdx.x >> 6);
  p2_dev<64, 64>(yA, wp + WP01, b01, g00, be00, st0, N0F, yC, st1, 16384, sstats,
                 blockIdx.x * 4 + wid, 8192);
}

__global__ __launch_bounds__(256) void p3s0_p2s1_kernel(
    const unsigned short* __restrict__ yC, const unsigned short* __restrict__ yB,
    const unsigned short* __restrict__ wp, const float* __restrict__ b02,
    const float* __restrict__ g01, const float* __restrict__ be01,
    const float* __restrict__ st1, const float* __restrict__ b11,
    const float* __restrict__ g10, const float* __restrict__ be10,
    const float* __restrict__ st3, unsigned short* __restrict__ yD,
    float* __restrict__ maxtA, float* __restrict__ st2, float* __restrict__ st4) {
  __shared__ float sstats[256];
  const int wid = rfl(threadIdx.x >> 6);
  if (blockIdx.x < 1024)
    p3_dev<64, 32>(yC, wp + WP02, b02, g01, be01, st1, N0F, maxtA, st2, sstats,
                   blockIdx.x * 4 + wid, 4096);
  else
    p2_dev<64, 96>(yB, wp + WP11, b11, g10, be10, st3, N1F, yD, st4, 32768, sstats,
                   (blockIdx.x - 1024) * 4 + wid, 8192);
}

__global__ __launch_bounds__(256) void out0_p3s1_kernel(
    const float* __restrict__ maxtA, const float* __restrict__ st2,
    const float* __restrict__ g02, const float* __restrict__ be02,
    const unsigned short* __restrict__ yD, const unsigned short* __restrict__ wp,
    const float* __restrict__ b12, const float* __restrict__ g11,
    const float* __restrict__ be11, const float* __restrict__ st4,
    float* __restrict__ maxtB, float* __restrict__ st5, float* __restrict__ outFeat) {
  __shared__ float sstats[256];
  const int wid = rfl(threadIdx.x >> 6);
  if (blockIdx.x < 1024)
    out_dev(maxtA, st2, g02, be02, N0F, outFeat, 0, sstats,
            blockIdx.x * 256 + threadIdx.x, 262144);
  else
    p3_dev<96, 64>(yD, wp + WP12, b12, g11, be11, st4, N1F, maxtB, st5, sstats,
                   (blockIdx.x - 1024) * 4 + wid, 8192);
}

__global__ __launch_bounds__(256) void out1_kernel(
    const float* __restrict__ maxtB, const float* __restrict__ st5,
    const float* __restrict__ g12, const float* __restrict__ be12,
    float* __restrict__ outFeat) {
  __shared__ float sstats[256];
  out_dev(maxtB, st5, g12, be12, N1F, outFeat, 128, sstats,
          blockIdx.x * 256 + threadIdx.x, 1048576);
}

}  // namespace

extern "C" void kernel_launch(void* const* d_in, const int* in_sizes, int n_in,
                              void* d_out, int out_size, void* d_ws, size_t ws_size,
                              hipStream_t stream) {
  const float* xyz  = (const float*)d_in[0];
  const float* feat = (const float*)d_in[1];
  const float* w00 = (const float*)d_in[2];  const float* b00 = (const float*)d_in[3];
  const float* g00 = (const float*)d_in[4];  const float* be00 = (const float*)d_in[5];
  const float* w01 = (const float*)d_in[6];  const float* b01 = (const float*)d_in[7];
  const float* g01 = (const float*)d_in[8];  const float* be01 = (const float*)d_in[9];
  const float* w02 = (const float*)d_in[10]; const float* b02 = (const float*)d_in[11];
  const float* g02 = (const float*)d_in[12]; const float* be02 = (const float*)d_in[13];
  const float* w10 = (const float*)d_in[14]; const float* b10 = (const float*)d_in[15];
  const float* g10 = (const float*)d_in[16]; const float* be10 = (const float*)d_in[17];
  const float* w11 = (const float*)d_in[18]; const float* b11 = (const float*)d_in[19];
  const float* g11 = (const float*)d_in[20]; const float* be11 = (const float*)d_in[21];
  const float* w12 = (const float*)d_in[22]; const float* b12 = (const float*)d_in[23];
  const float* g12 = (const float*)d_in[24]; const float* be12 = (const float*)d_in[25];

  float* ws = (float*)d_ws;
  int* idx0 = (int*)(ws + IDX0_OFF);
  int* idx1 = (int*)(ws + IDX1_OFF);
  float* stats = ws + STATS_OFF;
  unsigned short* wp = (unsigned short*)(ws + WP_OFF);
  float* maxtA = ws + MAXTA_OFF;
  float* maxtB = ws + MAXTB_OFF;
  unsigned short* featT = (unsigned short*)(ws + FEATT_OFF);
  unsigned short* yA = (unsigned short*)(ws + YA_OFF);
  unsigned short* yB = (unsigned short*)(ws + YB_OFF);
  unsigned short* yC = (unsigned short*)(ws + YC_OFF);
  unsigned short* yD = (unsigned short*)(ws + YD_OFF);
  (void)ws_size;  // 255 MB needed; prior rounds proved >= 268 MB available

  float* outF = (float*)d_out;          // new_xyz (B,S,3)
  float* outFeat = outF + B_ * S_ * 3;  // (B,256,S)

  float* st0 = stats + 0 * 8192;
  float* st1 = stats + 1 * 8192;
  float* st2 = stats + 2 * 8192;
  float* st3 = stats + 3 * 8192;
  float* st4 = stats + 4 * 8192;
  float* st5 = stats + 5 * 8192;

  prep_fps_kernel<<<1032, 256, 0, stream>>>(xyz, outF, feat, featT, w00, w01, w02, w10, w11,
                                            w12, wp, stats);
  ballq_kernel<<<4096, 256, 0, stream>>>(xyz, outF, idx0, idx1);
  p1_both_kernel<<<3072, 256, 0, stream>>>(xyz, featT, outF, idx0, idx1, wp, b00, b10, yA, yB,
                                           st0, st3);
  p2s0_kernel<<<2048, 256, 0, stream>>>(yA, wp, b01, g00, be00, st0, yC, st1);
  p3s0_p2s1_kernel<<<3072, 256, 0, stream>>>(yC, yB, wp, b02, g01, be01, st1, b11, g10, be10,
                                             st3, yD, maxtA, st2, st4);
  out0_p3s1_kernel<<<3072, 256, 0, stream>>>(maxtA, st2, g02, be02, yD, wp, b12, g11, be11,
                                             st4, maxtB, st5, outFeat);
  out1_kernel<<<4096, 256, 0, stream>>>(maxtB, st5, g12, be12, outFeat);
}

// Round 14
// 530.066 us; speedup vs baseline: 1.3544x; 1.3544x over previous
//
#include <hip/hip_runtime.h>

#define DEV __device__ __forceinline__

namespace {

typedef __attribute__((ext_vector_type(8))) short short8;
typedef __attribute__((ext_vector_type(4))) float f32x4;
typedef __attribute__((ext_vector_type(2))) float f32x2;

constexpr int B_ = 16, N_ = 4096, S_ = 512, CF_ = 64;
constexpr float EPS_ = 1e-5f;

// ---- ws layout (float units) ----
constexpr int IDX0_OFF  = 0;                      // B*S*32 ints
constexpr int IDX1_OFF  = 262144;                 // B*S*64 ints
constexpr int STATS_OFF = IDX1_OFF + 524288;      // 6 stages * 32 copies * 256 f
constexpr int WP_OFF    = STATS_OFF + 49152;      // 43008 ushorts = 21504 f
constexpr int MAXTA_OFF = WP_OFF + 21504;         // 8192*128 f
constexpr int MAXTB_OFF = MAXTA_OFF + 1048576;    // 8192*128 f
constexpr int FEATT_OFF = MAXTB_OFF + 1048576;    // 4194304 ushorts
constexpr int YA_OFF    = FEATT_OFF + 2097152;    // 262144*64 us = 8388608 f
constexpr int YB_OFF    = YA_OFF + 8388608;       // 524288*64 us = 16777216 f
constexpr int YC_OFF    = YB_OFF + 16777216;      // 262144*64 us = 8388608 f
constexpr int YD_OFF    = YC_OFF + 8388608;       // 524288*96 us = 25165824 f
// total = 255 MB (< proven 268 MB)

// packed-weight sub-offsets (ushort units)
constexpr int WP00 = 0,     WP01 = 6144,  WP02 = 10240;
constexpr int WP10 = 18432, WP11 = 24576, WP12 = 30720;

constexpr float N0F = (float)(B_ * S_ * 32);
constexpr float N1F = (float)(B_ * S_ * 64);

DEV int rfl(int x) { return __builtin_amdgcn_readfirstlane(x); }

DEV unsigned short f2bf(float x) {  // RNE float->bf16
  unsigned u = __float_as_uint(x);
  u += 0x7fff + ((u >> 16) & 1);
  return (unsigned short)(u >> 16);
}
DEV float bf2f(unsigned short u) { return __uint_as_float((unsigned)u << 16); }

// 64-lane f32 max reduce via DPP; full-wave max valid in lane 63.
DEV float dpp_max64(float v) {
  int m;
  m = __builtin_amdgcn_update_dpp(__float_as_int(v), __float_as_int(v), 0xB1, 0xf, 0xf, false);
  v = fmaxf(v, __int_as_float(m));
  m = __builtin_amdgcn_update_dpp(__float_as_int(v), __float_as_int(v), 0x4E, 0xf, 0xf, false);
  v = fmaxf(v, __int_as_float(m));
  m = __builtin_amdgcn_update_dpp(__float_as_int(v), __float_as_int(v), 0x141, 0xf, 0xf, false);
  v = fmaxf(v, __int_as_float(m));
  m = __builtin_amdgcn_update_dpp(__float_as_int(v), __float_as_int(v), 0x140, 0xf, 0xf, false);
  v = fmaxf(v, __int_as_float(m));
  m = __builtin_amdgcn_update_dpp(__float_as_int(v), __float_as_int(v), 0x142, 0xa, 0xf, false);
  v = fmaxf(v, __int_as_float(m));
  m = __builtin_amdgcn_update_dpp(__float_as_int(v), __float_as_int(v), 0x143, 0xc, 0xf, false);
  v = fmaxf(v, __int_as_float(m));
  return v;
}

// ===================== FPS body: R10 structure (256 thr, 16 pts/lane) ==========
DEV void fps_body(char* smem, const float* __restrict__ xyz, float* __restrict__ newxyz,
                  int b) {
  float* px = (float*)smem;                                       // 4096 f
  float* py = px + N_;
  float* pz = py + N_;                                            // ends at 49152 B
  unsigned long long* swk = (unsigned long long*)(smem + 49152);  // [2][4] = 64 B
  int* seq = (int*)(smem + 49216);                                // 512 ints
  const int t = threadIdx.x, lane = t & 63, wv = t >> 6;
  const float* xb = xyz + (size_t)b * N_ * 3;
  for (int i = t; i < N_; i += 256) {
    px[i] = xb[i * 3 + 0];
    py[i] = xb[i * 3 + 1];
    pz[i] = xb[i * 3 + 2];
  }
  __syncthreads();
  f32x2 Xp[8], Yp[8], Zp[8], Dp[8];
#pragma unroll
  for (int jp = 0; jp < 8; ++jp) {
    Xp[jp] = *reinterpret_cast<const f32x2*>(&px[t * 16 + jp * 2]);
    Yp[jp] = *reinterpret_cast<const f32x2*>(&py[t * 16 + jp * 2]);
    Zp[jp] = *reinterpret_cast<const f32x2*>(&pz[t * 16 + jp * 2]);
    Dp[jp] = f32x2{1e10f, 1e10f};
  }
  float cx = px[0], cy = py[0], cz = pz[0];
  if (t == 0) seq[0] = 0;
  for (int it = 1; it < S_; ++it) {
    const int p = it & 1;
    f32x2 bvp = {-1.0f, -1.0f};
    {
#pragma clang fp contract(off)
      const f32x2 c2x = {cx, cx}, c2y = {cy, cy}, c2z = {cz, cz};
#pragma unroll
      for (int jp = 0; jp < 8; ++jp) {
        const f32x2 dx = Xp[jp] - c2x, dy = Yp[jp] - c2y, dz = Zp[jp] - c2z;
        const f32x2 d = (dx * dx + dy * dy) + dz * dz;
        Dp[jp] = __builtin_elementwise_min(Dp[jp], d);
        bvp = __builtin_elementwise_max(bvp, Dp[jp]);
      }
    }
    const float bv = fmaxf(bvp.x, bvp.y);
    int bj = 0;
#pragma unroll
    for (int j = 15; j >= 0; --j) {
      const float dj = Dp[j >> 1][j & 1];
      bj = (dj == bv) ? j : bj;  // lowest tying j survives
    }
    const int bi = t * 16 + bj;
    // wave reduce: DPP max -> lane63, readlane broadcast, ballot tie-break
    const float mxl = dpp_max64(bv);
    const float mx = __int_as_float(__builtin_amdgcn_readlane(__float_as_int(mxl), 63));
    const unsigned long long tie = __ballot(bv == mx);
    const int srcLane = (int)__builtin_ctzll(tie);
    const int wbi = __builtin_amdgcn_readlane(bi, srcLane);
    if (lane == 0)
      swk[p * 4 + wv] = ((unsigned long long)__float_as_uint(mx) << 32) | (unsigned)(~wbi);
    __syncthreads();
    const unsigned long long k0 = swk[p * 4 + 0], k1 = swk[p * 4 + 1];
    const unsigned long long k2 = swk[p * 4 + 2], k3 = swk[p * 4 + 3];
    const unsigned long long ka = k0 > k1 ? k0 : k1;
    const unsigned long long kb = k2 > k3 ? k2 : k3;
    const unsigned long long kw = ka > kb ? ka : kb;
    const int ri = (int)(~(unsigned)kw);
    cx = px[ri]; cy = py[ri]; cz = pz[ri];
    if (t == 0) seq[it] = ri;
  }
  __syncthreads();
  for (int i = t; i < S_; i += 256) {
    const int ri = seq[i];
    newxyz[(size_t)(b * S_ + i) * 3 + 0] = px[ri];
    newxyz[(size_t)(b * S_ + i) * 3 + 1] = py[ri];
    newxyz[(size_t)(b * S_ + i) * 3 + 2] = pz[ri];
  }
}

// ===================== prep body (256 threads): stats zero + pack + transpose ============
DEV void prep_body(char* smem, int pb, const float* __restrict__ feat,
                   unsigned short* __restrict__ featT,
                   const float* __restrict__ w00, const float* __restrict__ w01,
                   const float* __restrict__ w02, const float* __restrict__ w10,
                   const float* __restrict__ w11, const float* __restrict__ w12,
                   unsigned short* __restrict__ wp, float* __restrict__ stats) {
  const int t = threadIdx.x;
  if (pb < 24) {
    for (int i = pb * 2048 + t; i < (pb + 1) * 2048; i += 256) stats[i] = 0.f;
  }
  {
    const int id = pb * 256 + t;
    const float* w = nullptr; int off = 0, KK = 0, CINW = 0, base = 0; bool perm = false;
    if (id < 768)       { w = w00; off = WP00; KK = 3; CINW = 67; perm = true;  base = 0; }
    else if (id < 1280) { w = w01; off = WP01; KK = 2; CINW = 64; perm = false; base = 768; }
    else if (id < 2304) { w = w02; off = WP02; KK = 2; CINW = 64; perm = false; base = 1280; }
    else if (id < 3072) { w = w10; off = WP10; KK = 3; CINW = 67; perm = true;  base = 2304; }
    else if (id < 3840) { w = w11; off = WP11; KK = 2; CINW = 64; perm = false; base = 3072; }
    else if (id < 5376) { w = w12; off = WP12; KK = 3; CINW = 96; perm = false; base = 3840; }
    if (w) {
      const int lid = id - base;
      const int lane = lid & 63, fr = lid >> 6;
      const int kk = fr % KK, nt = fr / KK;
      const int ccol = nt * 16 + (lane & 15);
      const int kbase = kk * 32 + (lane >> 4) * 8;
      unsigned short* dst = wp + off + (size_t)lid * 8;
#pragma unroll
      for (int j = 0; j < 8; ++j) {
        const int kq = kbase + j;
        int cin;
        if (perm) cin = (kq < 64) ? kq + 3 : (kq < 67 ? kq - 64 : -1);
        else      cin = (kq < CINW) ? kq : -1;
        float f = (cin >= 0) ? w[ccol * CINW + cin] : 0.f;
        dst[j] = f2bf(f);
      }
    }
  }
  {  // feat transpose (pb in [0,1024))
    unsigned short(*tile)[65] = (unsigned short(*)[65])smem;
    const int b = pb >> 6, nc = pb & 63;
    const int n0 = nc * 64;
    for (int i = t; i < 4096; i += 256) {
      int c = i >> 6, n = i & 63;
      tile[c][n] = f2bf(feat[((size_t)b * CF_ + c) * N_ + n0 + n]);
    }
    __syncthreads();
    for (int i = t; i < 4096; i += 256) {
      int n = i >> 6, c = i & 63;
      featT[((size_t)b * N_ + n0 + n) * 64 + c] = tile[c][n];
    }
  }
}

__global__ __launch_bounds__(256) void prep_fps_kernel(
    const float* __restrict__ xyz, float* __restrict__ newxyz,
    const float* __restrict__ feat, unsigned short* __restrict__ featT,
    const float* __restrict__ w00, const float* __restrict__ w01,
    const float* __restrict__ w02, const float* __restrict__ w10,
    const float* __restrict__ w11, const float* __restrict__ w12,
    unsigned short* __restrict__ wp, float* __restrict__ stats) {
  __shared__ __align__(16) char smem[51520];
  if (blockIdx.x < 16)
    fps_body(smem, xyz, newxyz, blockIdx.x);
  else
    prep_body(smem, blockIdx.x - 16, feat, featT, w00, w01, w02, w10, w11, w12, wp, stats);
}

// ===================== Ball query (both scales) =====================
DEV void ballq_dev(const float* __restrict__ xyz, const float* __restrict__ newxyz,
                   int* __restrict__ idx0, int* __restrict__ idx1, int* my, int gw, int NW) {
  const int lane = threadIdx.x & 63;
  for (int csp = gw; csp < 16384; csp += NW) {
    const int scale = csp >> 13;
    const int cs = csp & 8191;
    const int NS = scale ? 64 : 32;
    const float r2 = scale ? 0.4f * 0.4f : 0.2f * 0.2f;
    int* __restrict__ idx = scale ? idx1 : idx0;
    const int b = cs >> 9;
    const float cx = newxyz[(size_t)cs * 3 + 0];
    const float cy = newxyz[(size_t)cs * 3 + 1];
    const float cz = newxyz[(size_t)cs * 3 + 2];
    const float* xb = xyz + (size_t)b * N_ * 3;
    int cnt = 0;
    for (int base = 0; base < N_; base += 64) {
      if (cnt >= NS) break;
      const int i = base + lane;
      float d;
      {
#pragma clang fp contract(off)
        float dx = xb[i * 3 + 0] - cx, dy = xb[i * 3 + 1] - cy, dz = xb[i * 3 + 2] - cz;
        d = (dx * dx + dy * dy) + dz * dz;
      }
      const bool q = d < r2;
      const unsigned long long m = __ballot(q);
      if (q) {
        int pos = cnt + __popcll(m & ((1ull << lane) - 1ull));
        if (pos < NS) my[pos] = i;
      }
      cnt += __popcll(m);
    }
    const int c = cnt < NS ? cnt : NS;
    const int first = my[0];
    for (int j = lane; j < NS; j += 64) idx[(size_t)cs * NS + j] = (j < c) ? my[j] : first;
  }
}

__global__ __launch_bounds__(256) void ballq_kernel(const float* __restrict__ xyz,
                                                    const float* __restrict__ newxyz,
                                                    int* __restrict__ idx0,
                                                    int* __restrict__ idx1) {
  __shared__ int sbuf[4][64];
  const int wiv = threadIdx.x >> 6;
  const int gw = blockIdx.x * 4 + rfl(wiv);
  ballq_dev(xyz, newxyz, idx0, idx1, sbuf[wiv], gw, 16384);
}

// ===================== stats helpers (32-copy spread) =====================
template <int DS>
DEV void flush_stats(const float* ssum, const float* ssq, int lane, int slot,
                     float* __restrict__ sg) {
  constexpr int NTS = DS / 16;
  float* dst = sg + (size_t)slot * 256;
#pragma unroll
  for (int nt = 0; nt < NTS; ++nt) {
    float s = ssum[nt], q = ssq[nt];
    s += __shfl_xor(s, 16); q += __shfl_xor(q, 16);
    s += __shfl_xor(s, 32); q += __shfl_xor(q, 32);
    if (lane < 16) {
      atomicAdd(&dst[nt * 16 + lane], s);
      atomicAdd(&dst[DS + nt * 16 + lane], q);
    }
  }
}

DEV void reduce_stats_block(const float* __restrict__ sg, float* sstats, int t) {
  float s = 0.f;
#pragma unroll
  for (int c = 0; c < 32; ++c) s += sg[c * 256 + t];
  sstats[t] = s;
  __syncthreads();
}

// ===================== P1: gather + layer0 =====================
template <int K>
DEV void p1_dev(const float* __restrict__ xyz, const unsigned short* __restrict__ featT,
                const float* __restrict__ newxyz, const int* __restrict__ idx,
                const unsigned short* __restrict__ wp0, const float* __restrict__ b0,
                unsigned short* __restrict__ y0, float* __restrict__ stats_out,
                int gw, int NW) {
  const int lane = threadIdx.x & 63;
  const int col = lane & 15, khi = lane >> 4;
  constexpr int MT = (B_ * S_ * K) / 16;
  short8 bfr[12];
#pragma unroll
  for (int i = 0; i < 12; ++i)
    bfr[i] = *reinterpret_cast<const short8*>(wp0 + ((size_t)i * 64 + lane) * 8);
  float bb[4];
#pragma unroll
  for (int nt = 0; nt < 4; ++nt) bb[nt] = b0[nt * 16 + col];
  float ssum[4] = {0.f, 0.f, 0.f, 0.f}, ssq[4] = {0.f, 0.f, 0.f, 0.f};
  for (int mt = gw; mt < MT; mt += NW) {
    const int row = mt * 16 + col;
    const int cs = row / K;
    const int b = cs >> 9;
    const int pi = idx[row];
    const unsigned short* fr = featT + (((size_t)b * N_ + pi) << 6);
    const short8 a0 = *reinterpret_cast<const short8*>(fr + khi * 8);
    const short8 a1 = *reinterpret_cast<const short8*>(fr + 32 + khi * 8);
    short8 a2 = {0, 0, 0, 0, 0, 0, 0, 0};
    if (khi == 0) {
      const float* P = xyz + ((size_t)b * N_ + pi) * 3;
      const float* C = newxyz + (size_t)cs * 3;
      a2[0] = (short)f2bf(P[0] - C[0]);
      a2[1] = (short)f2bf(P[1] - C[1]);
      a2[2] = (short)f2bf(P[2] - C[2]);
    }
#pragma unroll
    for (int nt = 0; nt < 4; ++nt) {
      f32x4 a = {0.f, 0.f, 0.f, 0.f};
      a = __builtin_amdgcn_mfma_f32_16x16x32_bf16(a0, bfr[nt * 3 + 0], a, 0, 0, 0);
      a = __builtin_amdgcn_mfma_f32_16x16x32_bf16(a1, bfr[nt * 3 + 1], a, 0, 0, 0);
      a = __builtin_amdgcn_mfma_f32_16x16x32_bf16(a2, bfr[nt * 3 + 2], a, 0, 0, 0);
#pragma unroll
      for (int j = 0; j < 4; ++j) {
        const float y = a[j] + bb[nt];
        ssum[nt] += y; ssq[nt] += y * y;
        y0[(size_t)(mt * 16 + khi * 4 + j) * 64 + nt * 16 + col] = f2bf(y);
      }
    }
  }
  flush_stats<64>(ssum, ssq, lane, gw & 31, stats_out);
}

// ===================== P2: stats-reduce + norm -> layer -> yout =====================
template <int DIN, int DOUT>
DEV void p2_dev(const unsigned short* __restrict__ yin, const unsigned short* __restrict__ wp,
                const float* __restrict__ bias, const float* __restrict__ gprev,
                const float* __restrict__ bprev, const float* __restrict__ stats_prev, float n,
                unsigned short* __restrict__ yout, float* __restrict__ stats_out, int MT,
                float* sstats, int gw, int NW) {
  constexpr int KK = DIN / 32, NT = DOUT / 16;
  const int t = threadIdx.x, lane = t & 63;
  const int col = lane & 15, khi = lane >> 4;
  reduce_stats_block(stats_prev, sstats, t);
  short8 bfr[NT * KK];
#pragma unroll
  for (int i = 0; i < NT * KK; ++i)
    bfr[i] = *reinterpret_cast<const short8*>(wp + ((size_t)i * 64 + lane) * 8);
  float bb[NT];
#pragma unroll
  for (int nt = 0; nt < NT; ++nt) bb[nt] = bias[nt * 16 + col];
  float ar[KK][8], cr[KK][8];
#pragma unroll
  for (int kk = 0; kk < KK; ++kk)
#pragma unroll
    for (int j = 0; j < 8; ++j) {
      const int ch = kk * 32 + khi * 8 + j;
      const float mu = sstats[ch] / n;
      const float var = sstats[DIN + ch] / n - mu * mu;
      const float a = gprev[ch] / sqrtf(var + EPS_);
      ar[kk][j] = a;
      cr[kk][j] = bprev[ch] - mu * a;
    }
  float ssum[NT], ssq[NT];
#pragma unroll
  for (int nt = 0; nt < NT; ++nt) { ssum[nt] = 0.f; ssq[nt] = 0.f; }
  for (int mt = gw; mt < MT; mt += NW) {
    const size_t rb = (size_t)(mt * 16 + col) * DIN;
    short8 af[KK];
#pragma unroll
    for (int kk = 0; kk < KK; ++kk) {
      const short8 raw = *reinterpret_cast<const short8*>(yin + rb + kk * 32 + khi * 8);
#pragma unroll
      for (int j = 0; j < 8; ++j) {
        const float v = bf2f((unsigned short)raw[j]) * ar[kk][j] + cr[kk][j];
        af[kk][j] = (short)f2bf(fmaxf(v, 0.f));
      }
    }
#pragma unroll
    for (int nt = 0; nt < NT; ++nt) {
      f32x4 a = {0.f, 0.f, 0.f, 0.f};
#pragma unroll
      for (int kk = 0; kk < KK; ++kk)
        a = __builtin_amdgcn_mfma_f32_16x16x32_bf16(af[kk], bfr[nt * KK + kk], a, 0, 0, 0);
#pragma unroll
      for (int j = 0; j < 4; ++j) {
        const float y = a[j] + bb[nt];
        ssum[nt] += y; ssq[nt] += y * y;
        yout[(size_t)(mt * 16 + khi * 4 + j) * DOUT + nt * 16 + col] = f2bf(y);
      }
    }
  }
  flush_stats<DOUT>(ssum, ssq, lane, gw & 31, stats_out);
}

// ===================== P3: stats-reduce + norm -> layer2 -> stats + k-max ==========
template <int DIN, int K>
DEV void p3_dev(const unsigned short* __restrict__ yin, const unsigned short* __restrict__ wp,
                const float* __restrict__ bias, const float* __restrict__ gprev,
                const float* __restrict__ bprev, const float* __restrict__ stats_prev, float n,
                float* __restrict__ maxtmp, float* __restrict__ stats_out,
                float* sstats, int gw, int NW) {
  constexpr int KK = DIN / 32, NT = 8;
  const int t = threadIdx.x, lane = t & 63;
  const int col = lane & 15, khi = lane >> 4;
  reduce_stats_block(stats_prev, sstats, t);
  float bb[NT];
#pragma unroll
  for (int nt = 0; nt < NT; ++nt) bb[nt] = bias[nt * 16 + col];
  float ar[KK][8], cr[KK][8];
#pragma unroll
  for (int kk = 0; kk < KK; ++kk)
#pragma unroll
    for (int j = 0; j < 8; ++j) {
      const int ch = kk * 32 + khi * 8 + j;
      const float mu = sstats[ch] / n;
      const float var = sstats[DIN + ch] / n - mu * mu;
      const float a = gprev[ch] / sqrtf(var + EPS_);
      ar[kk][j] = a;
      cr[kk][j] = bprev[ch] - mu * a;
    }
  float ssum[NT], ssq[NT];
#pragma unroll
  for (int nt = 0; nt < NT; ++nt) { ssum[nt] = 0.f; ssq[nt] = 0.f; }
  for (int c = gw; c < B_ * S_; c += NW) {
    float mx[NT];
#pragma unroll
    for (int nt = 0; nt < NT; ++nt) mx[nt] = -3.4e38f;
#pragma unroll
    for (int m = 0; m < K / 16; ++m) {
      const size_t rb = (size_t)(c * K + m * 16 + col) * DIN;
      short8 af[KK];
#pragma unroll
      for (int kk = 0; kk < KK; ++kk) {
        const short8 raw = *reinterpret_cast<const short8*>(yin + rb + kk * 32 + khi * 8);
#pragma unroll
        for (int j = 0; j < 8; ++j) {
          const float v = bf2f((unsigned short)raw[j]) * ar[kk][j] + cr[kk][j];
          af[kk][j] = (short)f2bf(fmaxf(v, 0.f));
        }
      }
#pragma unroll
      for (int nt = 0; nt < NT; ++nt) {
        f32x4 a = {0.f, 0.f, 0.f, 0.f};
#pragma unroll
        for (int kk = 0; kk < KK; ++kk) {
          const short8 bf =
              *reinterpret_cast<const short8*>(wp + ((size_t)(nt * KK + kk) * 64 + lane) * 8);
          a = __builtin_amdgcn_mfma_f32_16x16x32_bf16(af[kk], bf, a, 0, 0, 0);
        }
#pragma unroll
        for (int j = 0; j < 4; ++j) {
          const float y = a[j] + bb[nt];
          ssum[nt] += y; ssq[nt] += y * y;
          mx[nt] = fmaxf(mx[nt], y);
        }
      }
    }
#pragma unroll
    for (int nt = 0; nt < NT; ++nt) {
      mx[nt] = fmaxf(mx[nt], __shfl_xor(mx[nt], 16));
      mx[nt] = fmaxf(mx[nt], __shfl_xor(mx[nt], 32));
    }
    if (lane < 16) {
#pragma unroll
      for (int nt = 0; nt < NT; ++nt) maxtmp[(size_t)c * 128 + nt * 16 + lane] = mx[nt];
    }
  }
  flush_stats<128>(ssum, ssq, lane, gw & 31, stats_out);
}

// ===================== out: stats-reduce + affine + transpose-write =====================
DEV void out_dev(const float* __restrict__ maxtmp, const float* __restrict__ stats2,
                 const float* __restrict__ g2, const float* __restrict__ be2, float n,
                 float* __restrict__ outf, int coff, float* sstats, int start, int stride) {
  reduce_stats_block(stats2, sstats, threadIdx.x);
  for (int i = start; i < B_ * 128 * S_; i += stride) {
    const int s = i & 511;
    const int o = (i >> 9) & 127;
    const int b = i >> 16;
    const float mu = sstats[o] / n;
    const float var = sstats[128 + o] / n - mu * mu;
    const float a = g2[o] / sqrtf(var + EPS_);
    const float c = be2[o] - mu * a;
    const float v = maxtmp[((size_t)(b * S_ + s)) * 128 + o];
    outf[((size_t)b * 256 + coff + o) * S_ + s] = a * v + c;
  }
}

// ===================== phase kernels =====================
__global__ __launch_bounds__(256) void p1_both_kernel(
    const float* __restrict__ xyz, const unsigned short* __restrict__ featT,
    const float* __restrict__ newxyz, const int* __restrict__ idx0,
    const int* __restrict__ idx1, const unsigned short* __restrict__ wp,
    const float* __restrict__ b00, const float* __restrict__ b10,
    unsigned short* __restrict__ yA, unsigned short* __restrict__ yB,
    float* __restrict__ st0, float* __restrict__ st3) {
  const int wid = rfl(threadIdx.x >> 6);
  if (blockIdx.x < 1024)
    p1_dev<32>(xyz, featT, newxyz, idx0, wp + WP00, b00, yA, st0, blockIdx.x * 4 + wid, 4096);
  else
    p1_dev<64>(xyz, featT, newxyz, idx1, wp + WP10, b10, yB, st3,
               (blockIdx.x - 1024) * 4 + wid, 8192);
}

__global__ __launch_bounds__(256) void p2s0_kernel(
    const unsigned short* __restrict__ yA, const unsigned short* __restrict__ wp,
    const float* __restrict__ b01, const float* __restrict__ g00,
    const float* __restrict__ be00, const float* __restrict__ st0,
    unsigned short* __restrict__ yC, float* __restrict__ st1) {
  __shared__ float sstats[256];
  const int wid = rfl(threadIdx.x >> 6);
  p2_dev<64, 64>(yA, wp + WP01, b01, g00, be00, st0, N0F, yC, st1, 16384, sstats,
                 blockIdx.x * 4 + wid, 8192);
}

__global__ __launch_bounds__(256) void p3s0_p2s1_kernel(
    const unsigned short* __restrict__ yC, const unsigned short* __restrict__ yB,
    const unsigned short* __restrict__ wp, const float* __restrict__ b02,
    const float* __restrict__ g01, const float* __restrict__ be01,
    const float* __restrict__ st1, const float* __restrict__ b11,
    const float* __restrict__ g10, const float* __restrict__ be10,
    const float* __restrict__ st3, unsigned short* __restrict__ yD,
    float* __restrict__ maxtA, float* __restrict__ st2, float* __restrict__ st4) {
  __shared__ float sstats[256];
  const int wid = rfl(threadIdx.x >> 6);
  if (blockIdx.x < 1024)
    p3_dev<64, 32>(yC, wp + WP02, b02, g01, be01, st1, N0F, maxtA, st2, sstats,
                   blockIdx.x * 4 + wid, 4096);
  else
    p2_dev<64, 96>(yB, wp + WP11, b11, g10, be10, st3, N1F, yD, st4, 32768, sstats,
                   (blockIdx.x - 1024) * 4 + wid, 8192);
}

__global__ __launch_bounds__(256) void out0_p3s1_kernel(
    const float* __restrict__ maxtA, const float* __restrict__ st2,
    const float* __restrict__ g02, const float* __restrict__ be02,
    const unsigned short* __restrict__ yD, const unsigned short* __restrict__ wp,
    const float* __restrict__ b12, const float* __restrict__ g11,
    const float* __restrict__ be11, const float* __restrict__ st4,
    float* __restrict__ maxtB, float* __restrict__ st5, float* __restrict__ outFeat) {
  __shared__ float sstats[256];
  const int wid = rfl(threadIdx.x >> 6);
  if (blockIdx.x < 1024)
    out_dev(maxtA, st2, g02, be02, N0F, outFeat, 0, sstats,
            blockIdx.x * 256 + threadIdx.x, 262144);
  else
    p3_dev<96, 64>(yD, wp + WP12, b12, g11, be11, st4, N1F, maxtB, st5, sstats,
                   (blockIdx.x - 1024) * 4 + wid, 8192);
}

__global__ __launch_bounds__(256) void out1_kernel(
    const float* __restrict__ maxtB, const float* __restrict__ st5,
    const float* __restrict__ g12, const float* __restrict__ be12,
    float* __restrict__ outFeat) {
  __shared__ float sstats[256];
  out_dev(maxtB, st5, g12, be12, N1F, outFeat, 128, sstats,
          blockIdx.x * 256 + threadIdx.x, 1048576);
}

}  // namespace

extern "C" void kernel_launch(void* const* d_in, const int* in_sizes, int n_in,
                              void* d_out, int out_size, void* d_ws, size_t ws_size,
                              hipStream_t stream) {
  const float* xyz  = (const float*)d_in[0];
  const float* feat = (const float*)d_in[1];
  const float* w00 = (const float*)d_in[2];  const float* b00 = (const float*)d_in[3];
  const float* g00 = (const float*)d_in[4];  const float* be00 = (const float*)d_in[5];
  const float* w01 = (const float*)d_in[6];  const float* b01 = (const float*)d_in[7];
  const float* g01 = (const float*)d_in[8];  const float* be01 = (const float*)d_in[9];
  const float* w02 = (const float*)d_in[10]; const float* b02 = (const float*)d_in[11];
  const float* g02 = (const float*)d_in[12]; const float* be02 = (const float*)d_in[13];
  const float* w10 = (const float*)d_in[14]; const float* b10 = (const float*)d_in[15];
  const float* g10 = (const float*)d_in[16]; const float* be10 = (const float*)d_in[17];
  const float* w11 = (const float*)d_in[18]; const float* b11 = (const float*)d_in[19];
  const float* g11 = (const float*)d_in[20]; const float* be11 = (const float*)d_in[21];
  const float* w12 = (const float*)d_in[22]; const float* b12 = (const float*)d_in[23];
  const float* g12 = (const float*)d_in[24]; const float* be12 = (const float*)d_in[25];

  float* ws = (float*)d_ws;
  int* idx0 = (int*)(ws + IDX0_OFF);
  int* idx1 = (int*)(ws + IDX1_OFF);
  float* stats = ws + STATS_OFF;
  unsigned short* wp = (unsigned short*)(ws + WP_OFF);
  float* maxtA = ws + MAXTA_OFF;
  float* maxtB = ws + MAXTB_OFF;
  unsigned short* featT = (unsigned short*)(ws + FEATT_OFF);
  unsigned short* yA = (unsigned short*)(ws + YA_OFF);
  unsigned short* yB = (unsigned short*)(ws + YB_OFF);
  unsigned short* yC = (unsigned short*)(ws + YC_OFF);
  unsigned short* yD = (unsigned short*)(ws + YD_OFF);
  (void)ws_size;  // 255 MB needed; prior rounds proved >= 268 MB available

  float* outF = (float*)d_out;          // new_xyz (B,S,3)
  float* outFeat = outF + B_ * S_ * 3;  // (B,256,S)

  float* st0 = stats + 0 * 8192;
  float* st1 = stats + 1 * 8192;
  float* st2 = stats + 2 * 8192;
  float* st3 = stats + 3 * 8192;
  float* st4 = stats + 4 * 8192;
  float* st5 = stats + 5 * 8192;

  prep_fps_kernel<<<1040, 256, 0, stream>>>(xyz, outF, feat, featT, w00, w01, w02, w10, w11,
                                            w12, wp, stats);
  ballq_kernel<<<4096, 256, 0, stream>>>(xyz, outF, idx0, idx1);
  p1_both_kernel<<<3072, 256, 0, stream>>>(xyz, featT, outF, idx0, idx1, wp, b00, b10, yA, yB,
                                           st0, st3);
  p2s0_kernel<<<2048, 256, 0, stream>>>(yA, wp, b01, g00, be00, st0, yC, st1);
  p3s0_p2s1_kernel<<<3072, 256, 0, stream>>>(yC, yB, wp, b02, g01, be01, st1, b11, g10, be10,
                                             st3, yD, maxtA, st2, st4);
  out0_p3s1_kernel<<<3072, 256, 0, stream>>>(maxtA, st2, g02, be02, yD, wp, b12, g11, be11,
                                             st4, maxtB, st5, outFeat);
  out1_kernel<<<4096, 256, 0, stream>>>(maxtB, st5, g12, be12, outFeat);
}